// Round 9
// baseline (177.511 us; speedup 1.0000x reference)
//
#include <hip/hip_runtime.h>
#include <hip/hip_bf16.h>

// IN_DIM=128, H=8, D=16, H*D=128.

typedef short short8 __attribute__((ext_vector_type(8)));
typedef float f32x4 __attribute__((ext_vector_type(4)));

__device__ __forceinline__ unsigned pack_bf16(float a, float b) {
    unsigned ua = __float_as_uint(a), ub = __float_as_uint(b);
    ua += 0x7fffu + ((ua >> 16) & 1u);          // RNE round to bf16
    ub += 0x7fffu + ((ub >> 16) & 1u);
    return (ua >> 16) | (ub & 0xffff0000u);
}

#define ULO(u) __uint_as_float((u) << 16)
#define UHI(u) __uint_as_float((u) & 0xffff0000u)

// ---------------------------------------------------------------------------
// prep_all: independent jobs partitioned by blockIdx:
//   [0,24):        prep_w -> swizzled bf16 WT images (32KB each)
//   [24,24+hB):    prep_h -> swizzled bf16 h image (256B/row, zero-padded)
//   [24+hB,...):   zero counts; first zero-block also zeros scan state
// ---------------------------------------------------------------------------
__global__ __launch_bounds__(256) void prep_all(
    const float* __restrict__ W0, const float* __restrict__ W1,
    const float* __restrict__ W2, const float* __restrict__ h,
    unsigned char* __restrict__ WTb, unsigned char* __restrict__ hb,
    int* __restrict__ counts, unsigned long long* __restrict__ state,
    int n, int hB, int nbS)
{
    const int b = blockIdx.x;
    if (b < 24) {
        const int w   = b >> 3;
        const int idx = (b & 7) * 256 + threadIdx.x;          // [0, 2048)
        const float* W = (w == 0) ? W0 : (w == 1) ? W1 : W2;
        unsigned char* wt = WTb + w * 32768;
        const int kp = idx >> 5;           // k-pair (2kp,2kp+1), [0,64)
        const int c4 = (idx & 31) * 4;     // col group
        const float* Wp = W + (size_t)(2 * kp) * 128 + c4;
        float4 wa = *(const float4*)Wp;
        float4 wb = *(const float4*)(Wp + 128);
        float a0[4] = {wa.x, wa.y, wa.z, wa.w};
        float a1[4] = {wb.x, wb.y, wb.z, wb.w};
#pragma unroll
        for (int i = 0; i < 4; ++i) {
            const int col = c4 + i;
            *(unsigned*)(wt + col * 256 + ((4 * kp) ^ ((col & 7) << 4))) =
                pack_bf16(a0[i], a1[i]);
        }
    } else if (b < 24 + hB) {
        const int idx = (b - 24) * 256 + threadIdx.x;          // [0, npad*32)
        const int row = idx >> 5;
        const int c4  = (idx & 31) * 4;
        float4 v = make_float4(0.f, 0.f, 0.f, 0.f);
        if (row < n) v = *(const float4*)(h + (size_t)row * 128 + c4);
        *(uint2*)(hb + row * 256 + ((c4 * 2) ^ ((row & 7) << 4))) =
            make_uint2(pack_bf16(v.x, v.y), pack_bf16(v.z, v.w));
    } else {
        const int zb = b - 24 - hB;
        const int i = zb * 256 + threadIdx.x;
        if (i < n) counts[i] = 0;
        if (zb == 0 && threadIdx.x < nbS) state[threadIdx.x] = 0ull;
    }
}

// ---------------------------------------------------------------------------
// hist_rank: histogram AND per-edge rank (the atomicAdd return) so the later
// fill needs no atomics.
// ---------------------------------------------------------------------------
__global__ void hist_rank(const int* __restrict__ dst, int* __restrict__ counts,
                          int* __restrict__ rank, int e) {
    int i = blockIdx.x * blockDim.x + threadIdx.x;
    if (i < e) rank[i] = atomicAdd(&counts[dst[i]], 1);
}

// ---------------------------------------------------------------------------
// scan_onepass: single-dispatch exclusive scan of counts -> offsets via
// decoupled lookback. state[b] = (value<<32)|flag; flag 0=none,1=agg,2=prefix.
// nb blocks (<=256) are all co-resident; HW dispatches in block order, so the
// lookback always terminates.
// ---------------------------------------------------------------------------
__global__ __launch_bounds__(256) void scan_onepass(
    const int* __restrict__ counts, unsigned long long* __restrict__ state,
    int* __restrict__ offsets, int nelem, int e)
{
    __shared__ int tmp[256];
    __shared__ int sbase;
    const int t = threadIdx.x, b = blockIdx.x;
    const int i = b * 256 + t;

    int v = (i < nelem) ? counts[i] : 0;
    tmp[t] = v;
    __syncthreads();
    for (int o = 1; o < 256; o <<= 1) {
        int u = (t >= o) ? tmp[t - o] : 0;
        __syncthreads();
        tmp[t] += u;
        __syncthreads();
    }
    const int agg = tmp[255];

    if (t == 0) {
        if (b == 0) {
            __hip_atomic_store(&state[0],
                ((unsigned long long)(unsigned)agg << 32) | 2ull,
                __ATOMIC_RELEASE, __HIP_MEMORY_SCOPE_AGENT);
            sbase = 0;
        } else {
            __hip_atomic_store(&state[b],
                ((unsigned long long)(unsigned)agg << 32) | 1ull,
                __ATOMIC_RELEASE, __HIP_MEMORY_SCOPE_AGENT);
            int run = 0, j = b - 1;
            while (true) {
                unsigned long long s = __hip_atomic_load(&state[j],
                    __ATOMIC_ACQUIRE, __HIP_MEMORY_SCOPE_AGENT);
                unsigned f = (unsigned)(s & 3ull);
                if (f == 2u) { run += (int)(s >> 32); break; }
                if (f == 1u) { run += (int)(s >> 32); --j; }
            }
            __hip_atomic_store(&state[b],
                ((unsigned long long)(unsigned)(run + agg) << 32) | 2ull,
                __ATOMIC_RELEASE, __HIP_MEMORY_SCOPE_AGENT);
            sbase = run;
        }
    }
    __syncthreads();
    const int base = sbase;
    if (i < nelem) offsets[i] = base + tmp[t] - v;
    if (i == nelem) offsets[nelem] = e;
}

// ---------------------------------------------------------------------------
// gemm_fill: every block FIRST grid-strides a chunk of the (atomic-free)
// edge fill, THEN computes its one MFMA GEMM tile. All blocks share the same
// resource shape, so fill scatter latency overlaps other blocks' MFMA work.
// GEMM: BM=64, 512 threads = 8 waves (2x4), 32x32/wave, K-loop 4 steps.
// Planes: Qb/Kb/Vb each [row][64] uints; uint c = cols (2c,2c+1).
// ---------------------------------------------------------------------------
__global__ __launch_bounds__(512) void gemm_fill(
    const unsigned char* __restrict__ hb, const unsigned char* __restrict__ WTb,
    const float* __restrict__ b0, const float* __restrict__ b1,
    const float* __restrict__ b2,
    unsigned* __restrict__ qb, unsigned* __restrict__ kb, unsigned* __restrict__ vb,
    const int* __restrict__ src, const int* __restrict__ dst,
    const int* __restrict__ rank, const int* __restrict__ offsets,
    int* __restrict__ srcSorted, int e)
{
    __shared__ __align__(16) unsigned char lds[49152];  // [0,16K): h  [16K,48K): WT/epi
    const int tid = threadIdx.x;

    // ---- fill chunk (grid-stride, no atomics) ----
    for (int i = blockIdx.x * 512 + tid; i < e; i += gridDim.x * 512)
        srcSorted[offsets[dst[i]] + rank[i]] = src[i];

    // ---- GEMM tile ----
    const int row0 = blockIdx.x * 64;
    {   // stage h tile: 16KB memcpy
        const uint4* s = (const uint4*)(hb + (size_t)row0 * 256);
        uint4* d = (uint4*)lds;
        d[tid]       = s[tid];
        d[tid + 512] = s[tid + 512];
    }

    const float* bs[3] = {b0, b1, b2};
    unsigned* planes[3] = {qb, kb, vb};

    const int lane = tid & 63, wave = tid >> 6;
    const int wr = wave >> 2, wc = wave & 3;       // 2x4 wave grid
    const int lr = lane & 15, lg = lane >> 4;

    for (int w = 0; w < 3; ++w) {
        __syncthreads();   // prev copy-out done / h-stage done (first iter)
        {   // stage WT: 32KB memcpy
            const uint4* s = (const uint4*)(WTb + w * 32768);
            uint4* d = (uint4*)(lds + 16384);
#pragma unroll
            for (int t = 0; t < 4; ++t) d[tid + t * 512] = s[tid + t * 512];
        }
        __syncthreads();

        f32x4 acc[2][2];
#pragma unroll
        for (int nt = 0; nt < 2; ++nt) {
            const float bv = bs[w][wc * 32 + nt * 16 + lr];
            acc[0][nt] = (f32x4){bv, bv, bv, bv};
            acc[1][nt] = (f32x4){bv, bv, bv, bv};
        }
#pragma unroll
        for (int ks = 0; ks < 4; ++ks) {
            const int kbyte = ks * 64 + lg * 16;
            short8 af[2], bf[2];
#pragma unroll
            for (int mt = 0; mt < 2; ++mt) {
                const int row = wr * 32 + mt * 16 + lr;
                af[mt] = *(const short8*)(lds + row * 256 + (kbyte ^ ((row & 7) << 4)));
            }
#pragma unroll
            for (int nt = 0; nt < 2; ++nt) {
                const int col = wc * 32 + nt * 16 + lr;
                bf[nt] = *(const short8*)(lds + 16384 + col * 256 + (kbyte ^ ((col & 7) << 4)));
            }
#pragma unroll
            for (int mt = 0; mt < 2; ++mt)
#pragma unroll
                for (int nt = 0; nt < 2; ++nt)
                    acc[mt][nt] = __builtin_amdgcn_mfma_f32_16x16x32_bf16(
                        af[mt], bf[nt], acc[mt][nt], 0, 0, 0);
        }

        __syncthreads();   // waves done reading WT; region becomes epi scratch
        {   // epi: even lanes write packed pair -> [row][colpair] (64x64 uints)
            unsigned* epi = (unsigned*)(lds + 16384);
#pragma unroll
            for (int mt = 0; mt < 2; ++mt)
#pragma unroll
                for (int nt = 0; nt < 2; ++nt) {
                    const int col = wc * 32 + nt * 16 + lr;
#pragma unroll
                    for (int r = 0; r < 4; ++r) {
                        const int row = wr * 32 + mt * 16 + lg * 4 + r;
                        const float v  = acc[mt][nt][r];
                        const float vn = __shfl_xor(v, 1);
                        if (!(lane & 1)) epi[row * 64 + (col >> 1)] = pack_bf16(v, vn);
                    }
                }
        }
        __syncthreads();
        {   // coalesced copy-out: 1024 uint4 = 64 rows x 256B
            const uint4* s = (const uint4*)(lds + 16384);
            uint4* d = (uint4*)(planes[w] + (size_t)row0 * 64);
            d[tid]       = s[tid];
            d[tid + 512] = s[tid + 512];
        }
    }
}

// ---------------------------------------------------------------------------
// Gather: one wave per node; lane l owns dims {2l,2l+1}; head = l>>3.
// Unroll 16 edges -> 32 outstanding 4B gathers per wave (latency hiding).
// Scores clamped to [-5,5] before softmax -> segment-max shift unnecessary.
// 0.25 scale folded into q.
// ---------------------------------------------------------------------------
__global__ __launch_bounds__(256) void mha_node(
    const unsigned* __restrict__ Qb, const unsigned* __restrict__ Kb,
    const unsigned* __restrict__ Vb,
    const int* __restrict__ offsets, const int* __restrict__ srcSorted,
    float* __restrict__ out, int n)
{
    const int lane = threadIdx.x & 63;
    const int node = (blockIdx.x * blockDim.x + threadIdx.x) >> 6;
    if (node >= n) return;

    const unsigned qu = Qb[(size_t)node * 64 + lane];
    const float qx = ULO(qu) * 0.25f, qy = UHI(qu) * 0.25f;
    const int beg = offsets[node], end = offsets[node + 1];

    float accx = 0.f, accy = 0.f, lsum = 0.f;

#define EDGE_COMPUTE(ku, vu)                                          \
    {                                                                 \
        float prod = fmaf(ULO(ku), qx, UHI(ku) * qy);                 \
        prod += __shfl_xor(prod, 1);                                  \
        prod += __shfl_xor(prod, 2);                                  \
        prod += __shfl_xor(prod, 4);                                  \
        float sc = fminf(5.f, fmaxf(-5.f, prod));                     \
        float p = __expf(sc);                                         \
        lsum += p;                                                    \
        accx = fmaf(p, ULO(vu), accx);                                \
        accy = fmaf(p, UHI(vu), accy);                                \
    }

    for (int j0 = beg; j0 < end; j0 += 64) {
        const int rem = end - j0;
        const int cnt = rem < 64 ? rem : 64;
        int myS = (lane < cnt) ? srcSorted[j0 + lane] : 0;

        int t = 0;
        for (; t + 16 <= cnt; t += 16) {
            unsigned ku[16], vu[16];
#pragma unroll
            for (int u = 0; u < 16; ++u) {
                int s = __shfl(myS, t + u);
                ku[u] = Kb[(size_t)s * 64 + lane];
                vu[u] = Vb[(size_t)s * 64 + lane];
            }
#pragma unroll
            for (int u = 0; u < 16; ++u) EDGE_COMPUTE(ku[u], vu[u]);
        }
        if (t + 8 <= cnt) {
            unsigned ku[8], vu[8];
#pragma unroll
            for (int u = 0; u < 8; ++u) {
                int s = __shfl(myS, t + u);
                ku[u] = Kb[(size_t)s * 64 + lane];
                vu[u] = Vb[(size_t)s * 64 + lane];
            }
#pragma unroll
            for (int u = 0; u < 8; ++u) EDGE_COMPUTE(ku[u], vu[u]);
            t += 8;
        }
        for (; t < cnt; ++t) {
            int s = __shfl(myS, t);
            unsigned ku0 = Kb[(size_t)s * 64 + lane];
            unsigned vu0 = Vb[(size_t)s * 64 + lane];
            EDGE_COMPUTE(ku0, vu0);
        }
    }

    float inv = (lsum > 0.f) ? 1.f / lsum : 0.f;
    *(float2*)(out + (size_t)node * 128 + lane * 2) =
        make_float2(accx * inv, accy * inv);
}

// ---------------------------------------------------------------------------
extern "C" void kernel_launch(void* const* d_in, const int* in_sizes, int n_in,
                              void* d_out, int out_size, void* d_ws, size_t ws_size,
                              hipStream_t stream) {
    const float* h  = (const float*)d_in[0];
    const float* Wq = (const float*)d_in[1];
    const float* bq = (const float*)d_in[2];
    const float* Wk = (const float*)d_in[3];
    const float* bk = (const float*)d_in[4];
    const float* Wv = (const float*)d_in[5];
    const float* bv = (const float*)d_in[6];
    const int*   src = (const int*)d_in[7];
    const int*   dst = (const int*)d_in[8];
    float* out = (float*)d_out;

    const int n = in_sizes[0] / 128;
    const int e = in_sizes[7];
    const int nblk = (n + 63) / 64;        // GEMM blocks
    const int npad = nblk * 64;            // padded rows
    const int nb = (n + 255) / 256;        // scan blocks (<=256; n=50000 -> 196)
    const int hB = npad / 8;               // prep_h blocks
    const int zB = nb;                     // counts-zero blocks

    char* ws = (char*)d_ws;
    size_t off = 0;
    auto alloc = [&](size_t bytes) {
        char* p = ws + off;
        off = (off + bytes + 255) & ~(size_t)255;
        return p;
    };
    unsigned char* hb  = (unsigned char*)alloc((size_t)npad * 256);
    unsigned char* WTb = (unsigned char*)alloc(3 * 32768);
    unsigned* Qb       = (unsigned*)alloc((size_t)npad * 64 * 4);
    unsigned* Kb       = (unsigned*)alloc((size_t)npad * 64 * 4);
    unsigned* Vb       = (unsigned*)alloc((size_t)npad * 64 * 4);
    int* counts        = (int*)alloc((size_t)n * sizeof(int));
    int* offsets       = (int*)alloc((size_t)(n + 1) * sizeof(int));
    int* rank          = (int*)alloc((size_t)e * sizeof(int));
    unsigned long long* state = (unsigned long long*)alloc((size_t)nb * 8);
    int* srcSorted     = (int*)alloc((size_t)e * sizeof(int));
    (void)ws_size; (void)n_in; (void)out_size;

    prep_all<<<24 + hB + zB, 256, 0, stream>>>(Wq, Wk, Wv, h, WTb, hb,
                                               counts, state, n, hB, nb);
    hist_rank<<<(e + 255) / 256, 256, 0, stream>>>(dst, counts, rank, e);
    scan_onepass<<<nb, 256, 0, stream>>>(counts, state, offsets, n, e);
    gemm_fill<<<nblk, 512, 0, stream>>>(hb, WTb, bq, bk, bv, Qb, Kb, Vb,
                                        src, dst, rank, offsets, srcSorted, e);
    mha_node<<<((size_t)n * 64 + 255) / 256, 256, 0, stream>>>(
        Qb, Kb, Vb, offsets, srcSorted, out, n);
}

// Round 10
// 143.697 us; speedup vs baseline: 1.2353x; 1.2353x over previous
//
#include <hip/hip_runtime.h>
#include <hip/hip_bf16.h>

// IN_DIM=128, H=8, D=16, H*D=128.

typedef short short8 __attribute__((ext_vector_type(8)));
typedef float f32x4 __attribute__((ext_vector_type(4)));

__device__ __forceinline__ unsigned pack_bf16(float a, float b) {
    unsigned ua = __float_as_uint(a), ub = __float_as_uint(b);
    ua += 0x7fffu + ((ua >> 16) & 1u);          // RNE round to bf16
    ub += 0x7fffu + ((ub >> 16) & 1u);
    return (ua >> 16) | (ub & 0xffff0000u);
}

#define ULO(u) __uint_as_float((u) << 16)
#define UHI(u) __uint_as_float((u) & 0xffff0000u)

// ---------------------------------------------------------------------------
// prep_all: [0,24): build swizzled bf16 WT images (32KB per W);
//           [24,...): zero counts.
// WT image: uint at [col*256 + ((4kp) ^ ((col&7)<<4))] = pack(W[2kp][col], W[2kp+1][col]).
// ---------------------------------------------------------------------------
__global__ __launch_bounds__(256) void prep_all(
    const float* __restrict__ W0, const float* __restrict__ W1,
    const float* __restrict__ W2, unsigned char* __restrict__ WTb,
    int* __restrict__ counts, int n)
{
    const int b = blockIdx.x;
    if (b < 24) {
        const int w   = b >> 3;
        const int idx = (b & 7) * 256 + threadIdx.x;          // [0, 2048)
        const float* W = (w == 0) ? W0 : (w == 1) ? W1 : W2;
        unsigned char* wt = WTb + w * 32768;
        const int kp = idx >> 5;           // k-pair (2kp,2kp+1), [0,64)
        const int c4 = (idx & 31) * 4;     // col group
        const float* Wp = W + (size_t)(2 * kp) * 128 + c4;
        float4 wa = *(const float4*)Wp;
        float4 wb = *(const float4*)(Wp + 128);
        float a0[4] = {wa.x, wa.y, wa.z, wa.w};
        float a1[4] = {wb.x, wb.y, wb.z, wb.w};
#pragma unroll
        for (int i = 0; i < 4; ++i) {
            const int col = c4 + i;
            *(unsigned*)(wt + col * 256 + ((4 * kp) ^ ((col & 7) << 4))) =
                pack_bf16(a0[i], a1[i]);
        }
    } else {
        const int i = (b - 24) * 256 + threadIdx.x;
        if (i < n) counts[i] = 0;
    }
}

// ---------------------------------------------------------------------------
// hist_rank: histogram AND per-edge rank (the atomicAdd return) so the later
// fill needs no atomics.
// ---------------------------------------------------------------------------
__global__ void hist_rank(const int* __restrict__ dst, int* __restrict__ counts,
                          int* __restrict__ rank, int e) {
    int i = blockIdx.x * blockDim.x + threadIdx.x;
    if (i < e) rank[i] = atomicAdd(&counts[dst[i]], 1);
}

__global__ void scan_block_sums(const int* __restrict__ counts, int* __restrict__ bsums, int nelem) {
    __shared__ int red[4];
    int i = blockIdx.x * 256 + threadIdx.x;
    int v = (i < nelem) ? counts[i] : 0;
#pragma unroll
    for (int o = 32; o > 0; o >>= 1) v += __shfl_down(v, o, 64);
    if ((threadIdx.x & 63) == 0) red[threadIdx.x >> 6] = v;
    __syncthreads();
    if (threadIdx.x == 0) bsums[blockIdx.x] = red[0] + red[1] + red[2] + red[3];
}

// scan_final2: computes its own exclusive prefix of bsums (nb<=256), then
// block-scans counts and writes offsets. offsets[nelem]=e by thread i==nelem.
__global__ void scan_final2(const int* __restrict__ counts, const int* __restrict__ bsums,
                            int* __restrict__ offsets, int nelem, int e) {
    __shared__ int tmp[256];
    __shared__ int red[4];
    const int t = threadIdx.x;

    int pre = (t < blockIdx.x) ? bsums[t] : 0;
#pragma unroll
    for (int o = 32; o > 0; o >>= 1) pre += __shfl_down(pre, o, 64);
    if ((t & 63) == 0) red[t >> 6] = pre;
    __syncthreads();
    const int base = red[0] + red[1] + red[2] + red[3];

    const int i = blockIdx.x * 256 + t;
    int v = (i < nelem) ? counts[i] : 0;
    tmp[t] = v;
    __syncthreads();
    for (int o = 1; o < 256; o <<= 1) {
        int u = (t >= o) ? tmp[t - o] : 0;
        __syncthreads();
        tmp[t] += u;
        __syncthreads();
    }
    if (i < nelem) offsets[i] = base + tmp[t] - v;
    if (i == nelem) offsets[nelem] = e;
}

// fill: no atomics — position comes from offsets[dst] + rank.
__global__ void fill_kernel(const int* __restrict__ src, const int* __restrict__ dst,
                            const int* __restrict__ rank, const int* __restrict__ offsets,
                            int* __restrict__ srcSorted, int e) {
    int i = blockIdx.x * blockDim.x + threadIdx.x;
    if (i < e) srcSorted[offsets[dst[i]] + rank[i]] = src[i];
}

// ---------------------------------------------------------------------------
// MFMA QKV GEMM, register-B variant. BM=64 rows/block, 512 threads = 8 waves
// (2x4); each wave a 32x32 tile = 2x2 frags of mfma_f32_16x16x32_bf16.
// - h staged fp32->bf16 swizzled directly into LDS (no prebuilt image).
// - A-frags loaded from LDS ONCE (shared across all 3 Ws).
// - B-frags loaded per-W straight from the prebuilt swizzled WT image in
//   global memory (L2-resident broadcast) -> no WT LDS staging, no stage
//   barriers.
// LDS 32KB: [0,16K) h image, [16K,32K) epilogue scratch.
// Planes: Qb/Kb/Vb each [row][64] uints; uint c = cols (2c,2c+1).
// ---------------------------------------------------------------------------
__global__ __launch_bounds__(512) void qkv_gemm(
    const float* __restrict__ h, const unsigned char* __restrict__ WTb,
    const float* __restrict__ b0, const float* __restrict__ b1,
    const float* __restrict__ b2,
    unsigned* __restrict__ qb, unsigned* __restrict__ kb, unsigned* __restrict__ vb,
    int n)
{
    __shared__ __align__(16) unsigned char lds[32768];
    const int tid  = threadIdx.x;
    const int row0 = blockIdx.x * 64;

    // ---- stage h tile directly: fp32 -> bf16, swizzled 256B rows ----
    for (int idx = tid; idx < 2048; idx += 512) {
        const int row = idx >> 5;
        const int c4  = (idx & 31) * 4;
        float4 v = make_float4(0.f, 0.f, 0.f, 0.f);
        if (row0 + row < n) v = *(const float4*)(h + (size_t)(row0 + row) * 128 + c4);
        *(uint2*)(lds + row * 256 + ((c4 * 2) ^ ((row & 7) << 4))) =
            make_uint2(pack_bf16(v.x, v.y), pack_bf16(v.z, v.w));
    }

    const float* bs[3] = {b0, b1, b2};
    unsigned* planes[3] = {qb, kb, vb};

    const int lane = tid & 63, wave = tid >> 6;
    const int wr = wave >> 2, wc = wave & 3;       // 2x4 wave grid
    const int lr = lane & 15, lg = lane >> 4;

    __syncthreads();

    // ---- A-frags once (depend only on h) ----
    short8 af[2][4];
#pragma unroll
    for (int mt = 0; mt < 2; ++mt)
#pragma unroll
        for (int ks = 0; ks < 4; ++ks) {
            const int row = wr * 32 + mt * 16 + lr;
            const int kbyte = ks * 64 + lg * 16;
            af[mt][ks] = *(const short8*)(lds + row * 256 + (kbyte ^ ((row & 7) << 4)));
        }

    for (int w = 0; w < 3; ++w) {
        // ---- B-frags straight from global WT image (L2 broadcast) ----
        short8 bf[2][4];
#pragma unroll
        for (int nt = 0; nt < 2; ++nt)
#pragma unroll
            for (int ks = 0; ks < 4; ++ks) {
                const int col = wc * 32 + nt * 16 + lr;
                const int kbyte = ks * 64 + lg * 16;
                bf[nt][ks] = *(const short8*)(
                    WTb + w * 32768 + col * 256 + (kbyte ^ ((col & 7) << 4)));
            }

        f32x4 acc[2][2];
#pragma unroll
        for (int nt = 0; nt < 2; ++nt) {
            const float bv = bs[w][wc * 32 + nt * 16 + lr];
            acc[0][nt] = (f32x4){bv, bv, bv, bv};
            acc[1][nt] = (f32x4){bv, bv, bv, bv};
        }
#pragma unroll
        for (int ks = 0; ks < 4; ++ks)
#pragma unroll
            for (int mt = 0; mt < 2; ++mt)
#pragma unroll
                for (int nt = 0; nt < 2; ++nt)
                    acc[mt][nt] = __builtin_amdgcn_mfma_f32_16x16x32_bf16(
                        af[mt][ks], bf[nt][ks], acc[mt][nt], 0, 0, 0);

        __syncthreads();   // epi region free (prev copy-out finished)
        {   // epi: even lanes write packed pair -> [row][colpair] (64x64 uints)
            unsigned* epi = (unsigned*)(lds + 16384);
#pragma unroll
            for (int mt = 0; mt < 2; ++mt)
#pragma unroll
                for (int nt = 0; nt < 2; ++nt) {
                    const int col = wc * 32 + nt * 16 + lr;
#pragma unroll
                    for (int r = 0; r < 4; ++r) {
                        const int row = wr * 32 + mt * 16 + lg * 4 + r;
                        const float v  = acc[mt][nt][r];
                        const float vn = __shfl_xor(v, 1);
                        if (!(lane & 1)) epi[row * 64 + (col >> 1)] = pack_bf16(v, vn);
                    }
                }
        }
        __syncthreads();
        {   // coalesced copy-out: 1024 uint4 = 64 rows x 256B
            const uint4* s = (const uint4*)(lds + 16384);
            uint4* d = (uint4*)(planes[w] + (size_t)row0 * 64);
            d[tid]       = s[tid];
            d[tid + 512] = s[tid + 512];
        }
    }
}

// ---------------------------------------------------------------------------
// Gather: one wave per node; lane l owns dims {2l,2l+1}; head = l>>3.
// Unroll-8 (round-8 verified optimum: 32 VGPR, 64% occupancy beats deeper
// per-wave ILP). Scores clamped to [-5,5] before softmax -> segment-max shift
// unnecessary (shift invariance). 0.25 scale folded into q.
// ---------------------------------------------------------------------------
__global__ __launch_bounds__(256) void mha_node(
    const unsigned* __restrict__ Qb, const unsigned* __restrict__ Kb,
    const unsigned* __restrict__ Vb,
    const int* __restrict__ offsets, const int* __restrict__ srcSorted,
    float* __restrict__ out, int n)
{
    const int lane = threadIdx.x & 63;
    const int node = (blockIdx.x * blockDim.x + threadIdx.x) >> 6;
    if (node >= n) return;

    const unsigned qu = Qb[(size_t)node * 64 + lane];
    const float qx = ULO(qu) * 0.25f, qy = UHI(qu) * 0.25f;
    const int beg = offsets[node], end = offsets[node + 1];

    float accx = 0.f, accy = 0.f, lsum = 0.f;

#define EDGE_COMPUTE(ku, vu)                                          \
    {                                                                 \
        float prod = fmaf(ULO(ku), qx, UHI(ku) * qy);                 \
        prod += __shfl_xor(prod, 1);                                  \
        prod += __shfl_xor(prod, 2);                                  \
        prod += __shfl_xor(prod, 4);                                  \
        float sc = fminf(5.f, fmaxf(-5.f, prod));                     \
        float p = __expf(sc);                                         \
        lsum += p;                                                    \
        accx = fmaf(p, ULO(vu), accx);                                \
        accy = fmaf(p, UHI(vu), accy);                                \
    }

    for (int j0 = beg; j0 < end; j0 += 64) {
        const int rem = end - j0;
        const int cnt = rem < 64 ? rem : 64;
        int myS = (lane < cnt) ? srcSorted[j0 + lane] : 0;

        int t = 0;
        for (; t + 8 <= cnt; t += 8) {
            unsigned ku[8], vu[8];
#pragma unroll
            for (int u = 0; u < 8; ++u) {
                int s = __shfl(myS, t + u);
                ku[u] = Kb[(size_t)s * 64 + lane];
                vu[u] = Vb[(size_t)s * 64 + lane];
            }
#pragma unroll
            for (int u = 0; u < 8; ++u) EDGE_COMPUTE(ku[u], vu[u]);
        }
        for (; t < cnt; ++t) {
            int s = __shfl(myS, t);
            unsigned ku0 = Kb[(size_t)s * 64 + lane];
            unsigned vu0 = Vb[(size_t)s * 64 + lane];
            EDGE_COMPUTE(ku0, vu0);
        }
    }

    float inv = (lsum > 0.f) ? 1.f / lsum : 0.f;
    *(float2*)(out + (size_t)node * 128 + lane * 2) =
        make_float2(accx * inv, accy * inv);
}

// ---------------------------------------------------------------------------
extern "C" void kernel_launch(void* const* d_in, const int* in_sizes, int n_in,
                              void* d_out, int out_size, void* d_ws, size_t ws_size,
                              hipStream_t stream) {
    const float* h  = (const float*)d_in[0];
    const float* Wq = (const float*)d_in[1];
    const float* bq = (const float*)d_in[2];
    const float* Wk = (const float*)d_in[3];
    const float* bk = (const float*)d_in[4];
    const float* Wv = (const float*)d_in[5];
    const float* bv = (const float*)d_in[6];
    const int*   src = (const int*)d_in[7];
    const int*   dst = (const int*)d_in[8];
    float* out = (float*)d_out;

    const int n = in_sizes[0] / 128;
    const int e = in_sizes[7];
    const int nblk = (n + 63) / 64;        // GEMM blocks
    const int npad = nblk * 64;            // padded rows
    const int nb = (n + 255) / 256;        // scan blocks (<=256; n=50000 -> 196)

    char* ws = (char*)d_ws;
    size_t off = 0;
    auto alloc = [&](size_t bytes) {
        char* p = ws + off;
        off = (off + bytes + 255) & ~(size_t)255;
        return p;
    };
    unsigned char* WTb = (unsigned char*)alloc(3 * 32768);
    unsigned* Qb       = (unsigned*)alloc((size_t)npad * 64 * 4);
    unsigned* Kb       = (unsigned*)alloc((size_t)npad * 64 * 4);
    unsigned* Vb       = (unsigned*)alloc((size_t)npad * 64 * 4);
    int* counts        = (int*)alloc((size_t)n * sizeof(int));
    int* offsets       = (int*)alloc((size_t)(n + 1) * sizeof(int));
    int* rank          = (int*)alloc((size_t)e * sizeof(int));
    int* bsums         = (int*)alloc((size_t)nb * sizeof(int));
    int* srcSorted     = (int*)alloc((size_t)e * sizeof(int));
    (void)ws_size; (void)n_in; (void)out_size;

    prep_all<<<24 + nb, 256, 0, stream>>>(Wq, Wk, Wv, WTb, counts, n);
    hist_rank<<<(e + 255) / 256, 256, 0, stream>>>(dst, counts, rank, e);
    scan_block_sums<<<nb, 256, 0, stream>>>(counts, bsums, n);
    scan_final2<<<nb, 256, 0, stream>>>(counts, bsums, offsets, n, e);
    fill_kernel<<<(e + 255) / 256, 256, 0, stream>>>(src, dst, rank, offsets, srcSorted, e);
    qkv_gemm<<<nblk, 512, 0, stream>>>(h, WTb, bq, bk, bv, Qb, Kb, Vb, n);
    mha_node<<<((size_t)n * 64 + 255) / 256, 256, 0, stream>>>(
        Qb, Kb, Vb, offsets, srcSorted, out, n);
}